// Round 2
// baseline (2431.776 us; speedup 1.0000x reference)
//
#include <hip/hip_runtime.h>
#include <cstdint>
#include <cstddef>

// ---------------------------------------------------------------------------
// MultiHeadAttention (per-head full-width projections), MI355X bf16 MFMA.
//
// Math rewrite:
//   z[b,s,e] = sum_h sum_t attn[b,h,s,t] * Vp[b,h,t,e] + ob[e]
//   Vp_h = x @ (Wv_h @ W0_h),  ob = b0 + sum_h bv_h @ W0_h  (softmax rows = 1)
// All GEMMs in "A[M,K] k-contig, Bt[N,K] k-contig" form.
// ---------------------------------------------------------------------------

#define DEV __device__ __forceinline__

using bf16x8 = __attribute__((ext_vector_type(8))) short;
using f32x4  = __attribute__((ext_vector_type(4))) float;
using su8    = __attribute__((ext_vector_type(8))) unsigned short;

DEV unsigned short f2b(float x) {            // fp32 -> bf16 round-nearest-even
  unsigned u = __builtin_bit_cast(unsigned, x);
  u += 0x7fffu + ((u >> 16) & 1u);
  return (unsigned short)(u >> 16);
}

// async global->LDS, 16B per lane; LDS dest is wave-uniform base + lane*16.
// NOTE: direct C-style casts -> proper addrspacecast (round-1 truncated the
// generic LDS pointer to 32 bits, which is NOT the LDS offset -> GPU fault).
DEV void gld_lds16(const void* g, void* l) {
  __builtin_amdgcn_global_load_lds(
      (const __attribute__((address_space(1))) void*)g,
      (__attribute__((address_space(3))) void*)l,
      16, 0, 0);
}

// ---------------------------------------------------------------------------
// Unified GEMM: C[z][m][n] (+)= scale * sum_k A[z][m][k] * Bt[z][n][k] (+bias)
// 128x128 tile, BK=32, 4 waves (2x2 of 64x64), mfma_f32_16x16x32_bf16.
// EPI: 0 = store bf16 (scale, +bias[col]); 1 = atomicAdd fp32; 2 = store fp32*scale
// ---------------------------------------------------------------------------
template <int EPI>
__global__ __launch_bounds__(256)
void gemm_bt_k(const unsigned short* __restrict__ A, long az, int lda,
               const unsigned short* __restrict__ Bt, long bz, int ldb,
               void* __restrict__ C, long cz, int ldc,
               int K, float scale, const float* __restrict__ bias, int biasz)
{
  __shared__ unsigned short lsA[128 * 32];
  __shared__ unsigned short lsB[128 * 32];

  const int tid  = threadIdx.x;
  const int lane = tid & 63;
  const int wid  = tid >> 6;
  const int wr   = wid >> 1, wc = wid & 1;
  const int z    = blockIdx.z;
  const int m0   = blockIdx.x * 128;
  const int n0   = blockIdx.y * 128;

  A  += (size_t)z * az;
  Bt += (size_t)z * bz;

  f32x4 acc[4][4];
#pragma unroll
  for (int i = 0; i < 4; i++)
#pragma unroll
    for (int j = 0; j < 4; j++) acc[i][j] = (f32x4){0.f, 0.f, 0.f, 0.f};

  const int srow = lane >> 2;        // 0..15: row within 16-row chunk
  const int scol = (lane & 3) * 8;   // k offset (elements)
  const int fr   = lane & 15;        // fragment row/col
  const int kq   = lane >> 4;        // k-quarter

  for (int k0 = 0; k0 < K; k0 += 32) {
    __syncthreads();                 // previous compute done before overwrite
#pragma unroll
    for (int i = 0; i < 2; i++) {
      int c = wid * 2 + i;           // chunk 0..7, wave-uniform
      int r = c * 16 + srow;
      gld_lds16(A  + (size_t)(m0 + r) * lda + (k0 + scol), &lsA[c * 512]);
      gld_lds16(Bt + (size_t)(n0 + r) * ldb + (k0 + scol), &lsB[c * 512]);
    }
    __syncthreads();                 // staged data visible (vmcnt drained)

    bf16x8 af[4], bfr[4];
#pragma unroll
    for (int mi = 0; mi < 4; mi++)
      af[mi] = *(const bf16x8*)&lsA[(wr * 64 + mi * 16 + fr) * 32 + kq * 8];
#pragma unroll
    for (int ni = 0; ni < 4; ni++)
      bfr[ni] = *(const bf16x8*)&lsB[(wc * 64 + ni * 16 + fr) * 32 + kq * 8];
#pragma unroll
    for (int mi = 0; mi < 4; mi++)
#pragma unroll
      for (int ni = 0; ni < 4; ni++)
        acc[mi][ni] = __builtin_amdgcn_mfma_f32_16x16x32_bf16(af[mi], bfr[ni], acc[mi][ni], 0, 0, 0);
  }

  const int rb = m0 + wr * 64 + (lane >> 4) * 4;   // C row: (lane>>4)*4 + reg
  const int cb = n0 + wc * 64 + (lane & 15);       // C col: lane&15

  if (EPI == 0) {
    unsigned short* Co = (unsigned short*)C + (size_t)z * cz;
#pragma unroll
    for (int mi = 0; mi < 4; mi++)
#pragma unroll
      for (int ni = 0; ni < 4; ni++) {
        int col = cb + ni * 16;
        float badd = bias ? bias[(size_t)z * biasz + col] : 0.f;
#pragma unroll
        for (int r = 0; r < 4; r++) {
          float v = acc[mi][ni][r] * scale + badd;
          Co[(size_t)(rb + mi * 16 + r) * ldc + col] = f2b(v);
        }
      }
  } else if (EPI == 1) {
    float* Co = (float*)C + (size_t)z * cz;
#pragma unroll
    for (int mi = 0; mi < 4; mi++)
#pragma unroll
      for (int ni = 0; ni < 4; ni++) {
        int col = cb + ni * 16;
#pragma unroll
        for (int r = 0; r < 4; r++)
          atomicAdd(&Co[(size_t)(rb + mi * 16 + r) * ldc + col], acc[mi][ni][r]);
      }
  } else {
    float* Co = (float*)C + (size_t)z * cz;
#pragma unroll
    for (int mi = 0; mi < 4; mi++)
#pragma unroll
      for (int ni = 0; ni < 4; ni++) {
        int col = cb + ni * 16;
#pragma unroll
        for (int r = 0; r < 4; r++)
          Co[(size_t)(rb + mi * 16 + r) * ldc + col] = acc[mi][ni][r] * scale;
      }
  }
}

// ---------------------------------------------------------------------------
// fp32 -> bf16 flat cast (vectorized x4)
// ---------------------------------------------------------------------------
__global__ __launch_bounds__(256)
void cast_k(const float* __restrict__ s, unsigned short* __restrict__ d, long n4)
{
  long i = (long)blockIdx.x * 256 + threadIdx.x;
  long stride = (long)gridDim.x * 256;
  for (; i < n4; i += stride) {
    float4 v = ((const float4*)s)[i];
    ushort4 o = { f2b(v.x), f2b(v.y), f2b(v.z), f2b(v.w) };
    ((ushort4*)d)[i] = o;
  }
}

// ---------------------------------------------------------------------------
// batched transpose-cast: src[z][R][C] fp32 -> dst[z][C][R] bf16, R=C=768
// ---------------------------------------------------------------------------
__global__ __launch_bounds__(256)
void tcast_k(const float* __restrict__ src, unsigned short* __restrict__ dst)
{
  __shared__ unsigned short t[64][65];
  const int R = 768;
  const int r0 = blockIdx.x * 64, c0 = blockIdx.y * 64;
  const float* s = src + (size_t)blockIdx.z * R * R;
  unsigned short* d = dst + (size_t)blockIdx.z * R * R;
  const int tx = threadIdx.x & 63, ty = threadIdx.x >> 6;
#pragma unroll
  for (int i = 0; i < 16; i++) {
    int r = ty * 16 + i;
    t[r][tx] = f2b(s[(size_t)(r0 + r) * R + c0 + tx]);
  }
  __syncthreads();
#pragma unroll
  for (int i = 0; i < 16; i++) {
    int r = ty * 16 + i;
    d[(size_t)(c0 + r) * R + r0 + tx] = t[tx][r];
  }
}

// ---------------------------------------------------------------------------
// output-bias partials: obp[c][f] = sum_{g in chunk c} bv[g] * W0[g*768+f]
// grid (3, 36), 256 thr; chunk = 256 g's. No atomics.
// ---------------------------------------------------------------------------
__global__ __launch_bounds__(256)
void obias1_k(const float* __restrict__ pbv, const float* __restrict__ pW0,
              float* __restrict__ obp)
{
  int f = blockIdx.x * 256 + threadIdx.x;
  int c = blockIdx.y;
  int g0 = c * 256;
  float a = 0.f;
#pragma unroll 4
  for (int g = g0; g < g0 + 256; ++g) a += pbv[g] * pW0[(size_t)g * 768 + f];
  obp[(size_t)c * 768 + f] = a;
}

// ob[f] = b0[f] + sum_c obp[c][f]    grid (3), 256 thr
__global__ __launch_bounds__(256)
void obias2_k(const float* __restrict__ pb0, const float* __restrict__ obp,
              float* __restrict__ ob)
{
  int f = blockIdx.x * 256 + threadIdx.x;
  float a = pb0[f];
#pragma unroll
  for (int c = 0; c < 36; ++c) a += obp[(size_t)c * 768 + f];
  ob[f] = a;
}

// ---------------------------------------------------------------------------
// out[b,s,:] = ob[:]  (float4 broadcast init; PV atomics accumulate on top)
// ---------------------------------------------------------------------------
__global__ __launch_bounds__(256)
void init_out_k(float4* __restrict__ out, const float4* __restrict__ ob, long n4)
{
  long i = (long)blockIdx.x * 256 + threadIdx.x;
  long stride = (long)gridDim.x * 256;
  for (; i < n4; i += stride) out[i] = ob[i % 192];
}

// ---------------------------------------------------------------------------
// row softmax: fp32 row of 2048 -> bf16 P in place (block = 256 thr = 4 waves)
// ---------------------------------------------------------------------------
__global__ __launch_bounds__(256)
void softmax_rows_k(float* __restrict__ Sb)
{
  const int t = threadIdx.x;
  float* rowf = Sb + ((size_t)blockIdx.y * 2048 + blockIdx.x) * 2048;
  float4 a = ((const float4*)rowf)[t * 2];
  float4 b = ((const float4*)rowf)[t * 2 + 1];
  float v[8] = {a.x, a.y, a.z, a.w, b.x, b.y, b.z, b.w};

  float m = v[0];
#pragma unroll
  for (int j = 1; j < 8; j++) m = fmaxf(m, v[j]);
#pragma unroll
  for (int o = 1; o < 64; o <<= 1) m = fmaxf(m, __shfl_xor(m, o));
  __shared__ float red[8];
  if ((t & 63) == 0) red[t >> 6] = m;
  __syncthreads();
  m = fmaxf(fmaxf(red[0], red[1]), fmaxf(red[2], red[3]));

  float e[8], s = 0.f;
#pragma unroll
  for (int j = 0; j < 8; j++) { e[j] = __expf(v[j] - m); s += e[j]; }
#pragma unroll
  for (int o = 1; o < 64; o <<= 1) s += __shfl_xor(s, o);
  if ((t & 63) == 0) red[4 + (t >> 6)] = s;
  __syncthreads();
  s = red[4] + red[5] + red[6] + red[7];
  float rs = 1.f / s;

  unsigned short* rowb = (unsigned short*)rowf;   // safe: all reads done above
  su8 o8;
#pragma unroll
  for (int j = 0; j < 8; j++) o8[j] = f2b(e[j] * rs);
  *(su8*)&rowb[t * 8] = o8;
}

// ---------------------------------------------------------------------------
extern "C" void kernel_launch(void* const* d_in, const int* in_sizes, int n_in,
                              void* d_out, int out_size, void* d_ws, size_t ws_size,
                              hipStream_t stream)
{
  const long E = 768, S = 2048, H = 12, NB = 4;
  const long EE = E * E;        // 589824
  const long SE = S * E;        // 1572864
  const long SS = S * S;        // 4194304

  const float* x   = (const float*)d_in[0];
  const float* Wq  = (const float*)d_in[1];
  const float* Wk  = (const float*)d_in[2];
  const float* Wv  = (const float*)d_in[3];
  const float* bq  = (const float*)d_in[4];
  const float* bk  = (const float*)d_in[5];
  const float* bv  = (const float*)d_in[6];
  const float* W0  = (const float*)d_in[7];
  const float* pb0 = (const float*)d_in[8];
  float* out = (float*)d_out;

  // --- workspace carve ---
  char* w = (char*)d_ws;
  size_t off = 0;
  auto take = [&](size_t bytes) -> char* {
    char* p = w + off;
    off += (bytes + 255) & ~(size_t)255;
    return p;
  };
  unsigned short* xb    = (unsigned short*)take(NB * SE * 2);  // x bf16       12.6MB
  unsigned short* WqTb  = (unsigned short*)take(H * EE * 2);   // Wq^T         14.2MB
  unsigned short* WkTb  = (unsigned short*)take(H * EE * 2);   // Wk^T         14.2MB
  unsigned short* WvpT  = (unsigned short*)take(H * EE * 2);   // (Wv@W0)^T    14.2MB
  unsigned short* Qb    = (unsigned short*)take(H * SE * 2);   // per-batch Q  37.7MB
  unsigned short* Kb    = (unsigned short*)take(H * SE * 2);   // per-batch K  37.7MB
  unsigned short* VpT   = (unsigned short*)take(H * SE * 2);   // per-batch VpT 37.7MB
  float*          obp   = (float*)take(36 * 768 * 4);          // bias partials
  float*          ob    = (float*)take(768 * 4);               // fused out bias
  // transient aliases (only live before the batch loop):
  unsigned short* Wvb   = Qb;   // Wv cast (14.2MB <= 37.7MB)
  unsigned short* W0Tb  = Kb;   // W0^T    (14.2MB <= 37.7MB)

  // Score buffer: largest head-group G whose fp32 S tiles fit in what's left.
  size_t rem = (ws_size > off) ? (ws_size - off) : 0;
  int G = 1;
  if      ((size_t)12 * SS * 4 <= rem) G = 12;
  else if ((size_t)4  * SS * 4 <= rem) G = 4;
  else if ((size_t)2  * SS * 4 <= rem) G = 2;
  float* Sb = (float*)take((size_t)G * SS * 4);

  // --- prep ---
  cast_k<<<2048, 256, 0, stream>>>(x,  xb,  NB * SE / 4);
  cast_k<<<2048, 256, 0, stream>>>(Wv, Wvb, H * EE / 4);
  tcast_k<<<dim3(12, 12, 12), 256, 0, stream>>>(Wq, WqTb);
  tcast_k<<<dim3(12, 12, 12), 256, 0, stream>>>(Wk, WkTb);
  tcast_k<<<dim3(12, 12, 12), 256, 0, stream>>>(W0, W0Tb);

  // WvpT[h][e][g] = sum_f W0T[h][e][f] * Wv[h][g][f]
  gemm_bt_k<0><<<dim3(6, 6, 12), 256, 0, stream>>>(
      W0Tb, EE, 768, Wvb, EE, 768, WvpT, EE, 768, 768, 1.f, nullptr, 0);

  obias1_k<<<dim3(3, 36), 256, 0, stream>>>(bv, W0, obp);
  obias2_k<<<3, 256, 0, stream>>>(pb0, obp, ob);
  init_out_k<<<2048, 256, 0, stream>>>((float4*)out, (const float4*)ob, NB * SE / 4);

  // --- per batch ---
  for (int b = 0; b < 4; b++) {
    const unsigned short* xbB = xb + (size_t)b * SE;

    // Q[h][s][f], K[h][s][f]  (bias folded in epilogue)
    gemm_bt_k<0><<<dim3(16, 6, 12), 256, 0, stream>>>(
        xbB, 0, 768, WqTb, EE, 768, Qb, SE, 768, 768, 1.f, bq, 768);
    gemm_bt_k<0><<<dim3(16, 6, 12), 256, 0, stream>>>(
        xbB, 0, 768, WkTb, EE, 768, Kb, SE, 768, 768, 1.f, bk, 768);
    // VpT[h][e][s] = sum_g WvpT[h][e][g] * x[s][g]
    gemm_bt_k<0><<<dim3(6, 16, 12), 256, 0, stream>>>(
        WvpT, EE, 768, xbB, 0, 768, VpT, SE, 2048, 768, 1.f, nullptr, 0);

    for (int g = 0; g < 12; g += G) {
      // S[z][i][j] = 0.125 * Q[g+z][i]·K[g+z][j]   (fp32 store)
      gemm_bt_k<2><<<dim3(16, 16, G), 256, 0, stream>>>(
          Qb + (size_t)g * SE, SE, 768, Kb + (size_t)g * SE, SE, 768,
          Sb, SS, 2048, 768, 0.125f, nullptr, 0);
      // P = softmax(S) rows, bf16 in place (row stride becomes 4096 ushorts)
      softmax_rows_k<<<dim3(2048, G), 256, 0, stream>>>(Sb);
      // out[b][s][e] += sum_z sum_j P[z][s][j] * VpT[g+z][e][j]
      gemm_bt_k<1><<<dim3(16, 6, G), 256, 0, stream>>>(
          (const unsigned short*)Sb, SS * 2, 4096, VpT + (size_t)g * SE, SE, 2048,
          out + (size_t)b * SE, 0, 768, 2048, 1.f, nullptr, 0);
    }
  }
}

// Round 3
// 2009.760 us; speedup vs baseline: 1.2100x; 1.2100x over previous
//
#include <hip/hip_runtime.h>
#include <cstdint>
#include <cstddef>

// ---------------------------------------------------------------------------
// MultiHeadAttention (per-head full-width projections), MI355X bf16 MFMA.
//
// Math rewrite:
//   softmax row-shift invariance kills q-side biases:
//     S_h = (x Mt_h^T x^T + 1·v_h^T)/8,  Mt_h = Wk_h Wq_h^T,  v_h = x (Wk_h^T bq_h)
//   z[b,s,:] = sum_h attn_h · Vp_h + ob,  Vp_h = x (Wv_h W0_h),
//   ob = b0 + sum_h bv_h W0_h   (softmax rows sum to 1)
//
// GEMM engine: 256x256 tile, BK=64, 8 waves, 8-phase interleave with counted
// vmcnt (T3+T4), XOR-swizzled LDS (T2), setprio around MFMA (T5).
// All GEMMs in "A[M,K] k-contig, Bt[N,K] k-contig" form.
// ---------------------------------------------------------------------------

#define DEV __device__ __forceinline__

using bf16x8 = __attribute__((ext_vector_type(8))) short;
using f32x4  = __attribute__((ext_vector_type(4))) float;
using su8    = __attribute__((ext_vector_type(8))) unsigned short;

DEV unsigned short f2b(float x) {            // fp32 -> bf16 round-nearest-even
  unsigned u = __builtin_bit_cast(unsigned, x);
  u += 0x7fffu + ((u >> 16) & 1u);
  return (unsigned short)(u >> 16);
}

DEV void gld_lds16(const void* g, void* l) {
  __builtin_amdgcn_global_load_lds(
      (const __attribute__((address_space(1))) void*)g,
      (__attribute__((address_space(3))) void*)l,
      16, 0, 0);
}

#define BAR() __builtin_amdgcn_s_barrier()
#define VMCNT4() asm volatile("s_waitcnt vmcnt(4)" ::: "memory")

// Stage one 16KB half (128 rows x 64 k-elements) of a tile operand into LDS.
// LDS dest is LINEAR (gld_lds writes base + lane*16); the XOR swizzle is
// applied to the GLOBAL source column so that LDS[swz(r,c)] = elem(r,c).
DEV void stage_half(const unsigned short* __restrict__ g, int ldx, int grow0,
                    int k0, char* region, int h, int wid, int lane) {
  const int rbase = h * 128 + wid * 16;
  const int colb = ((lane & 7) * 16) ^ ((lane >> 3) << 4);
#pragma unroll
  for (int j = 0; j < 2; ++j) {
    char* dst = region + (rbase + j * 8) * 128;
    const char* src = (const char*)(g + (size_t)(grow0 + rbase + j * 8 + (lane >> 3)) * ldx + k0) + colb;
    gld_lds16(src, dst);
  }
}

// Swizzled LDS fragment read: row r (0..255 within region), kel (0..63).
DEV bf16x8 ldread(const char* region, int r, int kel) {
  int lin = r * 128 + kel * 2;
  lin ^= (r & 7) << 4;
  return *(const bf16x8*)(region + lin);
}

// ---------------------------------------------------------------------------
// 256x256 8-phase GEMM: C[z][m][n] (+)= scale*(sum_k A[z][m][k]*Bt[z][n][k] (+bias))
// EPI: 0 = bf16 store (acc*scale + bias[col]); 1 = atomicAdd fp32;
//      2 = fp32 store (acc + bias[col]) * scale
// ---------------------------------------------------------------------------
template <int EPI>
__global__ __launch_bounds__(512, 1)
void gemm8_k(const unsigned short* __restrict__ A, long az, int lda,
             const unsigned short* __restrict__ Bt, long bz, int ldb,
             void* __restrict__ C, long cz, int ldc,
             int K, float scale, const float* __restrict__ bias, long biasz)
{
  extern __shared__ char smem[];      // 131072 B: [slot][A 32K | B 32K]
  const int tid  = threadIdx.x;
  const int lane = tid & 63;
  const int wid  = tid >> 6;          // 0..7
  const int wr   = wid >> 2;          // 0..1  (M half)
  const int wcn  = wid & 3;           // 0..3  (N quarter)
  const int z    = blockIdx.z;
  const int m0   = blockIdx.x * 256;
  const int n0   = blockIdx.y * 256;
  A  += (size_t)z * az;
  Bt += (size_t)z * bz;
  const int NT = K >> 6;

  f32x4 acc[8][4];
#pragma unroll
  for (int i = 0; i < 8; ++i)
#pragma unroll
    for (int j = 0; j < 4; ++j) acc[i][j] = (f32x4){0.f, 0.f, 0.f, 0.f};

  char* A0r = smem;
  char* B0r = smem + 32768;
  char* A1r = smem + 65536;
  char* B1r = smem + 65536 + 32768;

  // prologue: tile0 -> slot0 (A+B), tile1 A -> slot1
  stage_half(A,  lda, m0, 0, A0r, 0, wid, lane);
  stage_half(A,  lda, m0, 0, A0r, 1, wid, lane);
  stage_half(Bt, ldb, n0, 0, B0r, 0, wid, lane);
  stage_half(Bt, ldb, n0, 0, B0r, 1, wid, lane);
  if (NT > 1) {
    stage_half(A, lda, m0, 64, A1r, 0, wid, lane);
    stage_half(A, lda, m0, 64, A1r, 1, wid, lane);
    VMCNT4();                                   // tile0 fully landed
  } else {
    asm volatile("s_waitcnt vmcnt(0)" ::: "memory");
  }
  BAR();

  const int fr = lane & 15;
  const int kq = (lane >> 4) * 8;

  for (int t = 0; t < NT; ++t) {
    const int s = t & 1;
    const char* Ar = smem + s * 65536;
    const char* Br = Ar + 32768;
    char* Bn = smem + (s ^ 1) * 65536 + 32768;  // B(t+1) dest
    char* An = smem + s * 65536;                // A(t+2) dest (same slot A)
    const int kB = (t + 1) * 64, kA = (t + 2) * 64;

    bf16x8 aLo[4][2], aHi[4][2], bLo[2][2], bHi[2][2];

    // ---- P0: q(mh0,nh0) ----
    if (t + 1 < NT) stage_half(Bt, ldb, n0, kB, Bn, 0, wid, lane);
#pragma unroll
    for (int m = 0; m < 4; ++m)
#pragma unroll
      for (int ks = 0; ks < 2; ++ks)
        aLo[m][ks] = ldread(Ar, wr * 128 + m * 16 + fr, ks * 32 + kq);
#pragma unroll
    for (int n = 0; n < 2; ++n)
#pragma unroll
      for (int ks = 0; ks < 2; ++ks)
        bLo[n][ks] = ldread(Br, wcn * 64 + n * 16 + fr, ks * 32 + kq);
    BAR();
    __builtin_amdgcn_s_setprio(1);
#pragma unroll
    for (int m = 0; m < 4; ++m)
#pragma unroll
      for (int n = 0; n < 2; ++n)
#pragma unroll
        for (int ks = 0; ks < 2; ++ks)
          acc[m][n] = __builtin_amdgcn_mfma_f32_16x16x32_bf16(aLo[m][ks], bLo[n][ks], acc[m][n], 0, 0, 0);
    __builtin_amdgcn_s_setprio(0);
    BAR();

    // ---- P1: q(mh1,nh0) ----
    if (t + 1 < NT) stage_half(Bt, ldb, n0, kB, Bn, 1, wid, lane);
#pragma unroll
    for (int m = 0; m < 4; ++m)
#pragma unroll
      for (int ks = 0; ks < 2; ++ks)
        aHi[m][ks] = ldread(Ar, wr * 128 + 64 + m * 16 + fr, ks * 32 + kq);
    BAR();
    __builtin_amdgcn_s_setprio(1);
#pragma unroll
    for (int m = 0; m < 4; ++m)
#pragma unroll
      for (int n = 0; n < 2; ++n)
#pragma unroll
        for (int ks = 0; ks < 2; ++ks)
          acc[4 + m][n] = __builtin_amdgcn_mfma_f32_16x16x32_bf16(aHi[m][ks], bLo[n][ks], acc[4 + m][n], 0, 0, 0);
    __builtin_amdgcn_s_setprio(0);
    BAR();

    // ---- P2: q(mh0,nh1) ----
    if (t + 2 < NT) stage_half(A, lda, m0, kA, An, 0, wid, lane);
#pragma unroll
    for (int n = 0; n < 2; ++n)
#pragma unroll
      for (int ks = 0; ks < 2; ++ks)
        bHi[n][ks] = ldread(Br, wcn * 64 + 32 + n * 16 + fr, ks * 32 + kq);
    BAR();
    __builtin_amdgcn_s_setprio(1);
#pragma unroll
    for (int m = 0; m < 4; ++m)
#pragma unroll
      for (int n = 0; n < 2; ++n)
#pragma unroll
        for (int ks = 0; ks < 2; ++ks)
          acc[m][2 + n] = __builtin_amdgcn_mfma_f32_16x16x32_bf16(aLo[m][ks], bHi[n][ks], acc[m][2 + n], 0, 0, 0);
    __builtin_amdgcn_s_setprio(0);
    BAR();

    // ---- P3: q(mh1,nh1) ----
    if (t + 2 < NT) stage_half(A, lda, m0, kA, An, 1, wid, lane);
    BAR();
    __builtin_amdgcn_s_setprio(1);
#pragma unroll
    for (int m = 0; m < 4; ++m)
#pragma unroll
      for (int n = 0; n < 2; ++n)
#pragma unroll
        for (int ks = 0; ks < 2; ++ks)
          acc[4 + m][2 + n] = __builtin_amdgcn_mfma_f32_16x16x32_bf16(aHi[m][ks], bHi[n][ks], acc[4 + m][2 + n], 0, 0, 0);
    __builtin_amdgcn_s_setprio(0);
    VMCNT4();                                   // B(t+1) landed; A(t+2) flying
    BAR();
  }

  // ---- epilogue ----
  const int rb = m0 + wr * 128 + (lane >> 4) * 4;
  const int cb = n0 + wcn * 64 + fr;
  if (EPI == 0) {
    unsigned short* Co = (unsigned short*)C + (size_t)z * cz;
#pragma unroll
    for (int mi = 0; mi < 8; ++mi)
#pragma unroll
      for (int ni = 0; ni < 4; ++ni) {
        const int col = cb + ni * 16;
        const float badd = bias ? bias[(size_t)z * biasz + col] : 0.f;
#pragma unroll
        for (int r = 0; r < 4; ++r)
          Co[(size_t)(rb + mi * 16 + r) * ldc + col] = f2b(acc[mi][ni][r] * scale + badd);
      }
  } else if (EPI == 1) {
    float* Co = (float*)C + (size_t)z * cz;
#pragma unroll
    for (int mi = 0; mi < 8; ++mi)
#pragma unroll
      for (int ni = 0; ni < 4; ++ni) {
        const int col = cb + ni * 16;
#pragma unroll
        for (int r = 0; r < 4; ++r)
          atomicAdd(&Co[(size_t)(rb + mi * 16 + r) * ldc + col], acc[mi][ni][r] * scale);
      }
  } else {
    float* Co = (float*)C + (size_t)z * cz;
#pragma unroll
    for (int mi = 0; mi < 8; ++mi)
#pragma unroll
      for (int ni = 0; ni < 4; ++ni) {
        const int col = cb + ni * 16;
        const float badd = bias ? bias[(size_t)z * biasz + col] : 0.f;
#pragma unroll
        for (int r = 0; r < 4; ++r)
          Co[(size_t)(rb + mi * 16 + r) * ldc + col] = (acc[mi][ni][r] + badd) * scale;
      }
  }
}

// ---------------------------------------------------------------------------
__global__ __launch_bounds__(256)
void cast_k(const float* __restrict__ s, unsigned short* __restrict__ d, long n4)
{
  long i = (long)blockIdx.x * 256 + threadIdx.x;
  long stride = (long)gridDim.x * 256;
  for (; i < n4; i += stride) {
    float4 v = ((const float4*)s)[i];
    ushort4 o = { f2b(v.x), f2b(v.y), f2b(v.z), f2b(v.w) };
    ((ushort4*)d)[i] = o;
  }
}

__global__ __launch_bounds__(256)
void tcast_k(const float* __restrict__ src, unsigned short* __restrict__ dst)
{
  __shared__ unsigned short t[64][65];
  const int R = 768;
  const int r0 = blockIdx.x * 64, c0 = blockIdx.y * 64;
  const float* s = src + (size_t)blockIdx.z * R * R;
  unsigned short* d = dst + (size_t)blockIdx.z * R * R;
  const int tx = threadIdx.x & 63, ty = threadIdx.x >> 6;
#pragma unroll
  for (int i = 0; i < 16; i++) {
    int r = ty * 16 + i;
    t[r][tx] = f2b(s[(size_t)(r0 + r) * R + c0 + tx]);
  }
  __syncthreads();
#pragma unroll
  for (int i = 0; i < 16; i++) {
    int r = ty * 16 + i;
    d[(size_t)(c0 + r) * R + r0 + tx] = t[tx][r];
  }
}

// wv2[h][e] = sum_f Wk[h][e][f] * bq[h][f]     (one wave per (h,e))
__global__ __launch_bounds__(256)
void wv2_k(const float* __restrict__ Wk, const float* __restrict__ bq,
           float* __restrict__ wv2)
{
  int gw = blockIdx.x * 4 + (threadIdx.x >> 6);
  int lane = threadIdx.x & 63;
  int h = gw / 768, e = gw % 768;
  const float* wrow = Wk + ((size_t)h * 768 + e) * 768;
  const float* b = bq + (size_t)h * 768;
  float a = 0.f;
#pragma unroll
  for (int j = 0; j < 12; ++j) a += wrow[lane + j * 64] * b[lane + j * 64];
#pragma unroll
  for (int o = 1; o < 64; o <<= 1) a += __shfl_xor(a, o);
  if (!lane) wv2[gw] = a;
}

// vb[b][h][t] = sum_e x[b][t][e] * wv2[h][e]   (one wave per (b,t))
__global__ __launch_bounds__(256)
void vbias_k(const float* __restrict__ x, const float* __restrict__ wv2,
             float* __restrict__ vb)
{
  int gw = blockIdx.x * 4 + (threadIdx.x >> 6);
  int lane = threadIdx.x & 63;
  int b = gw >> 11, t = gw & 2047;
  const float* xr = x + ((size_t)b * 2048 + t) * 768;
  float xv[12];
#pragma unroll
  for (int j = 0; j < 12; ++j) xv[j] = xr[lane + j * 64];
#pragma unroll
  for (int h = 0; h < 12; ++h) {
    float a = 0.f;
#pragma unroll
    for (int j = 0; j < 12; ++j) a += xv[j] * wv2[(size_t)h * 768 + lane + j * 64];
#pragma unroll
    for (int o = 1; o < 64; o <<= 1) a += __shfl_xor(a, o);
    if (!lane) vb[((size_t)b * 12 + h) * 2048 + t] = a;
  }
}

__global__ __launch_bounds__(256)
void obias1_k(const float* __restrict__ pbv, const float* __restrict__ pW0,
              float* __restrict__ obp)
{
  int f = blockIdx.x * 256 + threadIdx.x;
  int c = blockIdx.y;
  int g0 = c * 256;
  float a = 0.f;
#pragma unroll 4
  for (int g = g0; g < g0 + 256; ++g) a += pbv[g] * pW0[(size_t)g * 768 + f];
  obp[(size_t)c * 768 + f] = a;
}

__global__ __launch_bounds__(256)
void obias2_k(const float* __restrict__ pb0, const float* __restrict__ obp,
              float* __restrict__ ob)
{
  int f = blockIdx.x * 256 + threadIdx.x;
  float a = pb0[f];
#pragma unroll
  for (int c = 0; c < 36; ++c) a += obp[(size_t)c * 768 + f];
  ob[f] = a;
}

__global__ __launch_bounds__(256)
void init_out_k(float4* __restrict__ out, const float4* __restrict__ ob, long n4)
{
  long i = (long)blockIdx.x * 256 + threadIdx.x;
  long stride = (long)gridDim.x * 256;
  for (; i < n4; i += stride) out[i] = ob[i % 192];
}

__global__ __launch_bounds__(256)
void softmax_rows_k(float* __restrict__ Sb)
{
  const int t = threadIdx.x;
  float* rowf = Sb + ((size_t)blockIdx.y * 2048 + blockIdx.x) * 2048;
  float4 a = ((const float4*)rowf)[t * 2];
  float4 b = ((const float4*)rowf)[t * 2 + 1];
  float v[8] = {a.x, a.y, a.z, a.w, b.x, b.y, b.z, b.w};

  float m = v[0];
#pragma unroll
  for (int j = 1; j < 8; j++) m = fmaxf(m, v[j]);
#pragma unroll
  for (int o = 1; o < 64; o <<= 1) m = fmaxf(m, __shfl_xor(m, o));
  __shared__ float red[8];
  if ((t & 63) == 0) red[t >> 6] = m;
  __syncthreads();
  m = fmaxf(fmaxf(red[0], red[1]), fmaxf(red[2], red[3]));

  float e[8], s = 0.f;
#pragma unroll
  for (int j = 0; j < 8; j++) { e[j] = __expf(v[j] - m); s += e[j]; }
#pragma unroll
  for (int o = 1; o < 64; o <<= 1) s += __shfl_xor(s, o);
  if ((t & 63) == 0) red[4 + (t >> 6)] = s;
  __syncthreads();
  s = red[4] + red[5] + red[6] + red[7];
  float rs = 1.f / s;

  unsigned short* rowb = (unsigned short*)rowf;
  su8 o8;
#pragma unroll
  for (int j = 0; j < 8; j++) o8[j] = f2b(e[j] * rs);
  *(su8*)&rowb[t * 8] = o8;
}

// ---------------------------------------------------------------------------
extern "C" void kernel_launch(void* const* d_in, const int* in_sizes, int n_in,
                              void* d_out, int out_size, void* d_ws, size_t ws_size,
                              hipStream_t stream)
{
  const long E = 768, S = 2048, H = 12, NB = 4;
  const long EE = E * E;
  const long SE = S * E;
  const long SS = S * S;
  const size_t LDSB = 131072;

  const float* x   = (const float*)d_in[0];
  const float* Wq  = (const float*)d_in[1];
  const float* Wk  = (const float*)d_in[2];
  const float* Wv  = (const float*)d_in[3];
  const float* bq  = (const float*)d_in[4];
  const float* bv  = (const float*)d_in[6];
  const float* W0  = (const float*)d_in[7];
  const float* pb0 = (const float*)d_in[8];
  float* out = (float*)d_out;

  char* w = (char*)d_ws;
  size_t off = 0;
  auto take = [&](size_t bytes) -> char* {
    char* p = w + off;
    off += (bytes + 255) & ~(size_t)255;
    return p;
  };
  unsigned short* xb   = (unsigned short*)take(NB * SE * 2);  // 12.6MB
  unsigned short* Mtb  = (unsigned short*)take(H * EE * 2);   // 14.2MB  Wk Wq^T
  unsigned short* WvpT = (unsigned short*)take(H * EE * 2);   // 14.2MB  (Wv W0)^T
  unsigned short* Tb   = (unsigned short*)take(H * SE * 2);   // 37.7MB  x Mt^T (per batch)
  unsigned short* VpT  = (unsigned short*)take(H * SE * 2);   // 37.7MB  per batch
  float* wv2 = (float*)take(H * E * 4);
  float* vb  = (float*)take(NB * H * S * 4);
  float* obp = (float*)take(36 * 768 * 4);
  float* ob  = (float*)take(768 * 4);
  // transient aliases (dead once Mtb/WvpT computed):
  unsigned short* Wqb  = Tb;              // 14.2MB
  unsigned short* Wkb  = Tb + H * EE;     // 14.2MB (fits: 28.3 <= 37.7)
  unsigned short* Wvb  = VpT;
  unsigned short* W0Tb = VpT + H * EE;

  size_t rem = (ws_size > off) ? (ws_size - off) : 0;
  int G = 1;
  if      ((size_t)12 * SS * 4 <= rem) G = 12;
  else if ((size_t)6  * SS * 4 <= rem) G = 6;
  else if ((size_t)4  * SS * 4 <= rem) G = 4;
  else if ((size_t)3  * SS * 4 <= rem) G = 3;
  else if ((size_t)2  * SS * 4 <= rem) G = 2;
  float* Sb = (float*)take((size_t)G * SS * 4);

  // --- prep ---
  cast_k<<<2048, 256, 0, stream>>>(x,  xb,  NB * SE / 4);
  cast_k<<<2048, 256, 0, stream>>>(Wq, Wqb, H * EE / 4);
  cast_k<<<2048, 256, 0, stream>>>(Wk, Wkb, H * EE / 4);
  cast_k<<<2048, 256, 0, stream>>>(Wv, Wvb, H * EE / 4);
  tcast_k<<<dim3(12, 12, 12), 256, 0, stream>>>(W0, W0Tb);
  wv2_k<<<H * 768 / 4, 256, 0, stream>>>(Wk, bq, wv2);
  vbias_k<<<NB * 2048 / 4, 256, 0, stream>>>(x, wv2, vb);

  // Mt[h][g][e] = sum_f Wk[h][g][f] Wq[h][e][f]
  gemm8_k<0><<<dim3(3, 3, 12), 512, LDSB, stream>>>(
      Wkb, EE, 768, Wqb, EE, 768, Mtb, EE, 768, 768, 1.f, nullptr, 0);
  // WvpT[h][e][g] = sum_f W0T[h][e][f] Wv[h][g][f]
  gemm8_k<0><<<dim3(3, 3, 12), 512, LDSB, stream>>>(
      W0Tb, EE, 768, Wvb, EE, 768, WvpT, EE, 768, 768, 1.f, nullptr, 0);

  obias1_k<<<dim3(3, 36), 256, 0, stream>>>(bv, W0, obp);
  obias2_k<<<3, 256, 0, stream>>>(pb0, obp, ob);
  init_out_k<<<2048, 256, 0, stream>>>((float4*)out, (const float4*)ob, NB * SE / 4);

  // --- per batch ---
  for (int b = 0; b < 4; b++) {
    const unsigned short* xbB = xb + (size_t)b * SE;

    // T[h][s][g] = sum_e x[s][e] Mt[h][g][e]
    gemm8_k<0><<<dim3(8, 3, 12), 512, LDSB, stream>>>(
        xbB, 0, 768, Mtb, EE, 768, Tb, SE, 768, 768, 1.f, nullptr, 0);
    // VpT[h][e][s] = sum_g WvpT[h][e][g] x[s][g]
    gemm8_k<0><<<dim3(3, 8, 12), 512, LDSB, stream>>>(
        WvpT, EE, 768, xbB, 0, 768, VpT, SE, 2048, 768, 1.f, nullptr, 0);

    for (int g = 0; g < 12; g += G) {
      // S[z][s][t] = (sum_g T[g0+z][s][g] x[t][g] + vb[b][g0+z][t]) / 8
      gemm8_k<2><<<dim3(8, 8, G), 512, LDSB, stream>>>(
          Tb + (size_t)g * SE, SE, 768, xbB, 0, 768,
          Sb, SS, 2048, 768, 0.125f, vb + ((size_t)b * 12 + g) * 2048, 2048);
      softmax_rows_k<<<dim3(2048, G), 256, 0, stream>>>(Sb);
      // out[b][s][e] += sum_t P[z][s][t] VpT[g0+z][e][t]
      gemm8_k<1><<<dim3(8, 3, G), 512, LDSB, stream>>>(
          (const unsigned short*)Sb, SS * 2, 4096, VpT + (size_t)g * SE, SE, 2048,
          out + (size_t)b * SE, 0, 768, 2048, 1.f, nullptr, 0);
    }
  }
}